// Round 1
// baseline (214.683 us; speedup 1.0000x reference)
//
#include <hip/hip_runtime.h>
#include <hip/hip_bf16.h>

typedef _Float16 half8 __attribute__((ext_vector_type(8)));
typedef float floatx4 __attribute__((ext_vector_type(4)));

#define MFMA16(a, b, c) __builtin_amdgcn_mfma_f32_16x16x32_f16(a, b, c, 0, 0, 0)

#define NEG_INF (-1e30f)

// ---------------------------------------------------------------------------
// Kernel 1: convert weights fp32 -> fp16, transposed so GEMM B-fragments read
// contiguous k-runs. wqt/wkt/wvt: [128 h][1024 d], wot: [1024 d][128 h].
// ---------------------------------------------------------------------------
__global__ __launch_bounds__(256) void convert_weights(
    const float* __restrict__ wq, const float* __restrict__ wk,
    const float* __restrict__ wv, const float* __restrict__ wo,
    _Float16* __restrict__ wqt, _Float16* __restrict__ wkt,
    _Float16* __restrict__ wvt, _Float16* __restrict__ wot) {
  int i = blockIdx.x * 256 + threadIdx.x;  // grid covers exactly 524288
  if (i < 3 * 131072) {
    int p = i / 131072, r = i % 131072;
    int h = r >> 10, d = r & 1023;
    const float* w = (p == 0) ? wq : (p == 1) ? wk : wv;
    _Float16* wt = (p == 0) ? wqt : (p == 1) ? wkt : wvt;
    wt[r] = (_Float16)w[d * 128 + h];
  } else {
    int r = i - 3 * 131072;
    int d = r >> 7, h = r & 127;
    wot[r] = (_Float16)wo[h * 1024 + d];
  }
}

// ---------------------------------------------------------------------------
// Kernel 2: fused QKV projection. x[8192,1024] fp32 -> Qh,Kh [8192,128] fp16,
// V transposed: Vt[(b*128+h)*2048+s]. Block = 64 rows x (3 proj x 128 cols).
// ---------------------------------------------------------------------------
__global__ __launch_bounds__(256) void qkv_gemm(
    const float* __restrict__ x, const _Float16* __restrict__ wqt,
    const _Float16* __restrict__ wkt, const _Float16* __restrict__ wvt,
    _Float16* __restrict__ Qh, _Float16* __restrict__ Kh,
    _Float16* __restrict__ Vt) {
  // stride 40 halfs = 80B: 16B-aligned, 2-way bank aliasing (free)
  __shared__ _Float16 A_lds[64 * 40];
  __shared__ _Float16 B_lds[3 * 128 * 40];
  int tid = threadIdx.x;
  int w = tid >> 6, lane = tid & 63, quad = lane >> 4, l16 = lane & 15;
  int m0 = blockIdx.x * 64;
  floatx4 zero = {0.f, 0.f, 0.f, 0.f};
  floatx4 acc[3][8];
#pragma unroll
  for (int p = 0; p < 3; p++)
#pragma unroll
    for (int t = 0; t < 8; t++) acc[p][t] = zero;

  int arow = tid >> 2, akoff = (tid & 3) * 8;

  for (int k0 = 0; k0 < 1024; k0 += 32) {
    // stage A tile (64x32), fp32 -> fp16 in-register
    {
      const float* src = x + (size_t)(m0 + arow) * 1024 + k0 + akoff;
      float4 f0 = *(const float4*)(src);
      float4 f1 = *(const float4*)(src + 4);
      half8 ah;
      ah[0] = (_Float16)f0.x; ah[1] = (_Float16)f0.y;
      ah[2] = (_Float16)f0.z; ah[3] = (_Float16)f0.w;
      ah[4] = (_Float16)f1.x; ah[5] = (_Float16)f1.y;
      ah[6] = (_Float16)f1.z; ah[7] = (_Float16)f1.w;
      *(half8*)&A_lds[arow * 40 + akoff] = ah;
    }
    // stage B tiles: 3 x [128 n][32 k]
#pragma unroll
    for (int i = 0; i < 6; i++) {
      int c = tid + i * 256;
      int p = c >> 9, r = c & 511;
      int n = r >> 2, koff = (r & 3) * 8;
      const _Float16* wsrc = (p == 0) ? wqt : (p == 1) ? wkt : wvt;
      *(half8*)&B_lds[p * 128 * 40 + n * 40 + koff] =
          *(const half8*)&wsrc[(size_t)n * 1024 + k0 + koff];
    }
    __syncthreads();
    half8 a = *(const half8*)&A_lds[(w * 16 + l16) * 40 + quad * 8];
#pragma unroll
    for (int p = 0; p < 3; p++)
#pragma unroll
      for (int t = 0; t < 8; t++) {
        half8 b = *(const half8*)&B_lds[p * 128 * 40 + (t * 16 + l16) * 40 + quad * 8];
        acc[p][t] = MFMA16(a, b, acc[p][t]);
      }
    __syncthreads();
  }
  // epilogue: C/D layout row = quad*4+reg, col = l16 (+16*t)
#pragma unroll
  for (int p = 0; p < 3; p++)
#pragma unroll
    for (int t = 0; t < 8; t++)
#pragma unroll
      for (int r = 0; r < 4; r++) {
        int row = m0 + w * 16 + quad * 4 + r;
        int col = t * 16 + l16;
        _Float16 v = (_Float16)acc[p][t][r];
        if (p == 0)
          Qh[(size_t)row * 128 + col] = v;
        else if (p == 1)
          Kh[(size_t)row * 128 + col] = v;
        else {
          int bb = row >> 11, s = row & 2047;
          Vt[((size_t)(bb * 128 + col)) * 2048 + s] = v;
        }
      }
}

// ---------------------------------------------------------------------------
// Kernel 3: flash attention. Grid (32 q-tiles, 4 batch). Block = 64 queries,
// wave owns 16. Online softmax fp32; P via LDS C->A layout round trip.
// ---------------------------------------------------------------------------
__global__ __launch_bounds__(256) void attn(
    const _Float16* __restrict__ Qh, const _Float16* __restrict__ Kh,
    const _Float16* __restrict__ Vt, _Float16* __restrict__ ctx) {
  __shared__ _Float16 K_lds[64 * 136];   // [key][feature], stride 136 (272B)
  __shared__ _Float16 V_lds[128 * 72];   // [head][key],   stride 72  (144B)
  __shared__ _Float16 P_lds[4 * 16 * 72];
  int tid = threadIdx.x;
  int w = tid >> 6, lane = tid & 63, quad = lane >> 4, l16 = lane & 15;
  int q0 = blockIdx.x * 64, b = blockIdx.y;
  const float scale = 0.08838834764831845f;  // 1/sqrt(128)

  // Q fragments live in registers across all K-tiles
  half8 aq[4];
  const _Float16* qbase = Qh + (size_t)(b * 2048 + q0 + w * 16 + l16) * 128;
#pragma unroll
  for (int c = 0; c < 4; c++) aq[c] = *(const half8*)&qbase[c * 32 + quad * 8];

  float m_r[4], l_r[4];
  floatx4 zero = {0.f, 0.f, 0.f, 0.f};
  floatx4 O[8];
#pragma unroll
  for (int r = 0; r < 4; r++) { m_r[r] = NEG_INF; l_r[r] = 0.f; }
#pragma unroll
  for (int t = 0; t < 8; t++) O[t] = zero;

  int nkt = blockIdx.x + 1;
  for (int kt = 0; kt < nkt; kt++) {
    int k0 = kt * 64;
#pragma unroll
    for (int i = 0; i < 4; i++) {  // K tile [64][128]
      int c = tid + i * 256;
      int key = c >> 4, f = (c & 15) * 8;
      *(half8*)&K_lds[key * 136 + f] =
          *(const half8*)&Kh[(size_t)(b * 2048 + k0 + key) * 128 + f];
    }
#pragma unroll
    for (int i = 0; i < 4; i++) {  // Vt tile [128][64]
      int c = tid + i * 256;
      int n = c >> 3, koff = (c & 7) * 8;
      *(half8*)&V_lds[n * 72 + koff] =
          *(const half8*)&Vt[(size_t)(b * 128 + n) * 2048 + k0 + koff];
    }
    __syncthreads();

    floatx4 sa[4];
#pragma unroll
    for (int t = 0; t < 4; t++) sa[t] = zero;
#pragma unroll
    for (int c = 0; c < 4; c++)
#pragma unroll
      for (int t = 0; t < 4; t++) {
        half8 bk = *(const half8*)&K_lds[(t * 16 + l16) * 136 + c * 32 + quad * 8];
        sa[t] = MFMA16(aq[c], bk, sa[t]);
      }

    bool diag = (k0 == q0);
    float p[4][4];
#pragma unroll
    for (int r = 0; r < 4; r++) {
      int query = q0 + w * 16 + quad * 4 + r;
      float mx = NEG_INF;
#pragma unroll
      for (int t = 0; t < 4; t++) {
        float s = sa[t][r] * scale;
        if (diag && (k0 + t * 16 + l16 > query)) s = NEG_INF;
        p[t][r] = s;
        mx = fmaxf(mx, s);
      }
#pragma unroll
      for (int off = 1; off < 16; off <<= 1) mx = fmaxf(mx, __shfl_xor(mx, off));
      float mnew = fmaxf(m_r[r], mx);
      float alpha = __expf(m_r[r] - mnew);
      float rs = 0.f;
#pragma unroll
      for (int t = 0; t < 4; t++) {
        float e = __expf(p[t][r] - mnew);
        p[t][r] = e;
        rs += e;
      }
#pragma unroll
      for (int off = 1; off < 16; off <<= 1) rs += __shfl_xor(rs, off);
      l_r[r] = alpha * l_r[r] + rs;
      m_r[r] = mnew;
#pragma unroll
      for (int t = 0; t < 8; t++) O[t][r] *= alpha;
    }

    // P: C-layout -> LDS -> A-layout (wave-private region, no barrier needed)
#pragma unroll
    for (int r = 0; r < 4; r++)
#pragma unroll
      for (int t = 0; t < 4; t++)
        P_lds[w * 16 * 72 + (quad * 4 + r) * 72 + t * 16 + l16] = (_Float16)p[t][r];

#pragma unroll
    for (int c2 = 0; c2 < 2; c2++) {
      half8 ap = *(const half8*)&P_lds[w * 16 * 72 + l16 * 72 + c2 * 32 + quad * 8];
#pragma unroll
      for (int t = 0; t < 8; t++) {
        half8 bv = *(const half8*)&V_lds[(t * 16 + l16) * 72 + c2 * 32 + quad * 8];
        O[t] = MFMA16(ap, bv, O[t]);
      }
    }
    __syncthreads();
  }

#pragma unroll
  for (int t = 0; t < 8; t++)
#pragma unroll
    for (int r = 0; r < 4; r++) {
      int q = q0 + w * 16 + quad * 4 + r;
      float v = O[t][r] / l_r[r];
      ctx[(size_t)(b * 2048 + q) * 128 + t * 16 + l16] = (_Float16)v;
    }
}

// ---------------------------------------------------------------------------
// Kernel 4: out projection ctx[8192,128] x wo[128,1024] -> out fp32.
// ---------------------------------------------------------------------------
__global__ __launch_bounds__(256) void out_gemm(
    const _Float16* __restrict__ ctx, const _Float16* __restrict__ wot,
    float* __restrict__ out) {
  __shared__ _Float16 A_lds[64 * 40];
  __shared__ _Float16 B_lds[128 * 40];
  int tid = threadIdx.x;
  int w = tid >> 6, lane = tid & 63, quad = lane >> 4, l16 = lane & 15;
  int m0 = blockIdx.x * 64, n0 = blockIdx.y * 128;
  floatx4 zero = {0.f, 0.f, 0.f, 0.f};
  floatx4 acc[8];
#pragma unroll
  for (int t = 0; t < 8; t++) acc[t] = zero;

  for (int k0 = 0; k0 < 128; k0 += 32) {
    {
      int arow = tid >> 2, akoff = (tid & 3) * 8;
      *(half8*)&A_lds[arow * 40 + akoff] =
          *(const half8*)&ctx[(size_t)(m0 + arow) * 128 + k0 + akoff];
    }
#pragma unroll
    for (int i = 0; i < 2; i++) {
      int c = tid + i * 256;
      int n = c >> 2, koff = (c & 3) * 8;
      *(half8*)&B_lds[n * 40 + koff] =
          *(const half8*)&wot[(size_t)(n0 + n) * 128 + k0 + koff];
    }
    __syncthreads();
    half8 a = *(const half8*)&A_lds[(w * 16 + l16) * 40 + quad * 8];
#pragma unroll
    for (int t = 0; t < 8; t++) {
      half8 bf = *(const half8*)&B_lds[(t * 16 + l16) * 40 + quad * 8];
      acc[t] = MFMA16(a, bf, acc[t]);
    }
    __syncthreads();
  }
#pragma unroll
  for (int t = 0; t < 8; t++)
#pragma unroll
    for (int r = 0; r < 4; r++) {
      int row = m0 + w * 16 + quad * 4 + r;
      out[(size_t)row * 1024 + n0 + t * 16 + l16] = acc[t][r];
    }
}

// ---------------------------------------------------------------------------
extern "C" void kernel_launch(void* const* d_in, const int* in_sizes, int n_in,
                              void* d_out, int out_size, void* d_ws, size_t ws_size,
                              hipStream_t stream) {
  const float* x = (const float*)d_in[0];
  const float* wq = (const float*)d_in[1];
  const float* wk = (const float*)d_in[2];
  const float* wv = (const float*)d_in[3];
  const float* wo = (const float*)d_in[4];
  char* ws = (char*)d_ws;
  _Float16* wqt = (_Float16*)(ws + 0);
  _Float16* wkt = (_Float16*)(ws + 262144);
  _Float16* wvt = (_Float16*)(ws + 524288);
  _Float16* wot = (_Float16*)(ws + 786432);
  _Float16* Qh  = (_Float16*)(ws + 1048576);
  _Float16* Kh  = (_Float16*)(ws + 1048576 + 2097152);
  _Float16* Vt  = (_Float16*)(ws + 1048576 + 2 * 2097152);
  _Float16* ctxh = (_Float16*)(ws + 1048576 + 3 * 2097152);
  float* out = (float*)d_out;

  convert_weights<<<2048, 256, 0, stream>>>(wq, wk, wv, wo, wqt, wkt, wvt, wot);
  qkv_gemm<<<128, 256, 0, stream>>>(x, wqt, wkt, wvt, Qh, Kh, Vt);
  attn<<<dim3(32, 4), 256, 0, stream>>>(Qh, Kh, Vt, ctxh);
  out_gemm<<<dim3(128, 8), 256, 0, stream>>>(ctxh, wot, out);
}